// Round 1
// baseline (4051.361 us; speedup 1.0000x reference)
//
#include <hip/hip_runtime.h>
#include <math.h>

#define DIM 128
#define H 5
#define C 10
#define HC 50
#define NG 256
#define NEG_SLOPE 0.2f

// ---------------- init ----------------
__global__ void k_init(float* __restrict__ m, float* __restrict__ denom,
                       float* __restrict__ out_node, float* __restrict__ gsum,
                       float* __restrict__ cnt, int n) {
  int stride = gridDim.x * blockDim.x;
  int total = n * HC;  // largest region
  for (int i = blockIdx.x * blockDim.x + threadIdx.x; i < total; i += stride) {
    out_node[i] = 0.f;
    if (i < n * H) { m[i] = -INFINITY; denom[i] = 0.f; }
    if (i < NG * HC) gsum[i] = 0.f;
    if (i < NG) cnt[i] = 0.f;
  }
}

// ---------------- xw = x @ W ----------------
__global__ void k_xw(const float* __restrict__ x, const float* __restrict__ W,
                     float* __restrict__ xw, int n) {
  __shared__ float sW[DIM * HC];  // 25.6 KB
  for (int i = threadIdx.x; i < DIM * HC; i += blockDim.x) sW[i] = W[i];
  __syncthreads();
  int total = n * HC;
  int stride = gridDim.x * blockDim.x;
  for (int idx = blockIdx.x * blockDim.x + threadIdx.x; idx < total; idx += stride) {
    int row = idx / HC, col = idx - row * HC;
    const float* xr = x + (size_t)row * DIM;
    float acc = 0.f;
#pragma unroll 8
    for (int k = 0; k < DIM; ++k) acc += xr[k] * sW[k * HC + col];
    xw[idx] = acc;
  }
}

// ---------------- a_src / a_dst ----------------
__global__ void k_att(const float* __restrict__ xw, const float* __restrict__ att_src,
                      const float* __restrict__ att_dst, float* __restrict__ a_src,
                      float* __restrict__ a_dst, int n) {
  int total = n * H;
  int stride = gridDim.x * blockDim.x;
  for (int idx = blockIdx.x * blockDim.x + threadIdx.x; idx < total; idx += stride) {
    int node = idx / H, h = idx - node * H;
    const float* row = xw + (size_t)node * HC + h * C;
    float s = 0.f, d = 0.f;
#pragma unroll
    for (int c = 0; c < C; ++c) {
      float v = row[c];
      s += v * att_src[h * C + c];
      d += v * att_dst[h * C + c];
    }
    a_src[idx] = s;
    a_dst[idx] = d;
  }
}

__device__ inline float lrelu(float z) { return z > 0.f ? z : NEG_SLOPE * z; }

// monotonic float atomic max: works for any sign mix, init -inf
__device__ inline void atomicMaxF(float* addr, float v) {
  if (v >= 0.f)
    atomicMax((int*)addr, __float_as_int(v));
  else
    atomicMin((unsigned int*)addr, __float_as_uint(v));
}

// ---------------- edge pass 1: segment max ----------------
__global__ void k_edge_max(const int* __restrict__ src, const int* __restrict__ dst,
                           const float* __restrict__ a_src, const float* __restrict__ a_dst,
                           float* __restrict__ m, int E_, int n) {
  int total = (E_ + n) * H;
  int stride = gridDim.x * blockDim.x;
  for (int idx = blockIdx.x * blockDim.x + threadIdx.x; idx < total; idx += stride) {
    int e = idx / H, h = idx - e * H;
    int j, i;
    if (e < E_) { j = src[e]; i = dst[e]; } else { j = i = e - E_; }
    float z = lrelu(a_src[j * H + h] + a_dst[i * H + h]);
    atomicMaxF(&m[i * H + h], z);
  }
}

// ---------------- edge pass 2: segment sum of exp ----------------
__global__ void k_edge_den(const int* __restrict__ src, const int* __restrict__ dst,
                           const float* __restrict__ a_src, const float* __restrict__ a_dst,
                           const float* __restrict__ m, float* __restrict__ denom, int E_, int n) {
  int total = (E_ + n) * H;
  int stride = gridDim.x * blockDim.x;
  for (int idx = blockIdx.x * blockDim.x + threadIdx.x; idx < total; idx += stride) {
    int e = idx / H, h = idx - e * H;
    int j, i;
    if (e < E_) { j = src[e]; i = dst[e]; } else { j = i = e - E_; }
    float z = lrelu(a_src[j * H + h] + a_dst[i * H + h]);
    atomicAdd(&denom[i * H + h], __expf(z - m[i * H + h]));
  }
}

// ---------------- edge pass 3: alpha-weighted aggregation ----------------
__global__ void k_edge_agg(const int* __restrict__ src, const int* __restrict__ dst,
                           const float* __restrict__ a_src, const float* __restrict__ a_dst,
                           const float* __restrict__ m, const float* __restrict__ denom,
                           const float* __restrict__ xw, float* __restrict__ out_node,
                           int E_, int n) {
  int total = (E_ + n) * H;
  int stride = gridDim.x * blockDim.x;
  for (int idx = blockIdx.x * blockDim.x + threadIdx.x; idx < total; idx += stride) {
    int e = idx / H, h = idx - e * H;
    int j, i;
    if (e < E_) { j = src[e]; i = dst[e]; } else { j = i = e - E_; }
    float z = lrelu(a_src[j * H + h] + a_dst[i * H + h]);
    float alpha = __expf(z - m[i * H + h]) / denom[i * H + h];
    const float* xr = xw + (size_t)j * HC + h * C;
    float* orow = out_node + (size_t)i * HC + h * C;
#pragma unroll
    for (int c = 0; c < C; ++c) atomicAdd(&orow[c], alpha * xr[c]);
  }
}

// ---------------- bias + ELU + mean-pool accumulate ----------------
__global__ void k_pool(const float* __restrict__ out_node, const float* __restrict__ bias,
                       const int* __restrict__ batch, float* __restrict__ gsum,
                       float* __restrict__ cnt, int n) {
  int total = n * HC;
  int stride = gridDim.x * blockDim.x;
  for (int idx = blockIdx.x * blockDim.x + threadIdx.x; idx < total; idx += stride) {
    int node = idx / HC, hc = idx - node * HC;
    float v = out_node[idx] + bias[hc];
    v = v > 0.f ? v : __expf(v) - 1.f;
    int b = batch[node];
    atomicAdd(&gsum[b * HC + hc], v);
    if (hc == 0) atomicAdd(&cnt[b], 1.f);
  }
}

// ---------------- mean + linear + sigmoid ----------------
__global__ void k_final(const float* __restrict__ gsum, const float* __restrict__ cnt,
                        const float* __restrict__ lin_w, const float* __restrict__ lin_b,
                        float* __restrict__ out) {
  int g = blockIdx.x;
  int t = threadIdx.x;  // 64 threads
  float c = fmaxf(cnt[g], 1.f);
  float p = 0.f;
  if (t < HC) {
    float hv = gsum[g * HC + t] / c;
    out[g * HC + t] = hv;
    p = hv * lin_w[t];
  }
#pragma unroll
  for (int off = 32; off > 0; off >>= 1) p += __shfl_down(p, off);
  if (t == 0) out[NG * HC + g] = 1.f / (1.f + __expf(-(p + lin_b[0])));
}

extern "C" void kernel_launch(void* const* d_in, const int* in_sizes, int n_in,
                              void* d_out, int out_size, void* d_ws, size_t ws_size,
                              hipStream_t stream) {
  const float* x       = (const float*)d_in[0];
  const float* W       = (const float*)d_in[1];
  const float* att_src = (const float*)d_in[2];
  const float* att_dst = (const float*)d_in[3];
  const float* bias    = (const float*)d_in[4];
  const float* lin_w   = (const float*)d_in[5];
  const float* lin_b   = (const float*)d_in[6];
  const int*   eidx    = (const int*)d_in[7];
  const int*   batch   = (const int*)d_in[8];

  int n  = in_sizes[0] / DIM;   // 100000
  int E_ = in_sizes[7] / 2;     // 1600000
  const int* srcp = eidx;
  const int* dstp = eidx + E_;

  // workspace layout (floats)
  float* ws       = (float*)d_ws;
  float* xw       = ws;                         // n*HC
  float* a_src    = xw + (size_t)n * HC;        // n*H
  float* a_dst    = a_src + (size_t)n * H;      // n*H
  float* m        = a_dst + (size_t)n * H;      // n*H
  float* denom    = m + (size_t)n * H;          // n*H
  float* out_node = denom + (size_t)n * H;      // n*HC
  float* gsum     = out_node + (size_t)n * HC;  // NG*HC
  float* cnt      = gsum + NG * HC;             // NG

  float* out = (float*)d_out;

  const int T = 256;
  int etotH = (E_ + n) * H;

  k_init<<<4096, T, 0, stream>>>(m, denom, out_node, gsum, cnt, n);
  k_xw<<<2560, T, 0, stream>>>(x, W, xw, n);
  k_att<<<(n * H + T - 1) / T, T, 0, stream>>>(xw, att_src, att_dst, a_src, a_dst, n);
  k_edge_max<<<(etotH + T - 1) / T, T, 0, stream>>>(srcp, dstp, a_src, a_dst, m, E_, n);
  k_edge_den<<<(etotH + T - 1) / T, T, 0, stream>>>(srcp, dstp, a_src, a_dst, m, denom, E_, n);
  k_edge_agg<<<(etotH + T - 1) / T, T, 0, stream>>>(srcp, dstp, a_src, a_dst, m, denom, xw, out_node, E_, n);
  k_pool<<<(n * HC + T - 1) / T, T, 0, stream>>>(out_node, bias, batch, gsum, cnt, n);
  k_final<<<NG, 64, 0, stream>>>(gsum, cnt, lin_w, lin_b, out);
}

// Round 2
// 919.262 us; speedup vs baseline: 4.4072x; 4.4072x over previous
//
#include <hip/hip_runtime.h>
#include <math.h>

#define DIM 128
#define H 5
#define C 10
#define HC 50
#define NG 256
#define NEG_SLOPE 0.2f

// ---------------- zero init ----------------
__global__ void k_zero(int* __restrict__ count, float* __restrict__ gsum,
                       float* __restrict__ cnt, int n) {
  int i = blockIdx.x * blockDim.x + threadIdx.x;
  int stride = gridDim.x * blockDim.x;
  for (int k = i; k < n + 1; k += stride) count[k] = 0;
  if (i < NG * HC) gsum[i] = 0.f;
  if (i < NG) cnt[i] = 0.f;
}

// ---------------- xw = x @ W ----------------
__global__ void k_xw(const float* __restrict__ x, const float* __restrict__ W,
                     float* __restrict__ xw, int n) {
  __shared__ float sW[DIM * HC];  // 25.6 KB
  for (int i = threadIdx.x; i < DIM * HC; i += blockDim.x) sW[i] = W[i];
  __syncthreads();
  int total = n * HC;
  int stride = gridDim.x * blockDim.x;
  for (int idx = blockIdx.x * blockDim.x + threadIdx.x; idx < total; idx += stride) {
    int row = idx / HC, col = idx - row * HC;
    const float* xr = x + (size_t)row * DIM;
    float acc = 0.f;
#pragma unroll 8
    for (int k = 0; k < DIM; ++k) acc += xr[k] * sW[k * HC + col];
    xw[idx] = acc;
  }
}

// ---------------- a_src / a_dst ----------------
__global__ void k_att(const float* __restrict__ xw, const float* __restrict__ att_src,
                      const float* __restrict__ att_dst, float* __restrict__ a_src,
                      float* __restrict__ a_dst, int n) {
  int total = n * H;
  int stride = gridDim.x * blockDim.x;
  for (int idx = blockIdx.x * blockDim.x + threadIdx.x; idx < total; idx += stride) {
    int node = idx / H, h = idx - node * H;
    const float* row = xw + (size_t)node * HC + h * C;
    float s = 0.f, d = 0.f;
#pragma unroll
    for (int c = 0; c < C; ++c) {
      float v = row[c];
      s += v * att_src[h * C + c];
      d += v * att_dst[h * C + c];
    }
    a_src[idx] = s;
    a_dst[idx] = d;
  }
}

// ---------------- CSR build: histogram ----------------
__global__ void k_hist(const int* __restrict__ dst, int* __restrict__ count, int E_) {
  int stride = gridDim.x * blockDim.x;
  for (int e = blockIdx.x * blockDim.x + threadIdx.x; e < E_; e += stride)
    atomicAdd(&count[dst[e]], 1);
}

// ---------------- CSR build: 2-level exclusive scan ----------------
__global__ void k_scan1(const int* __restrict__ count, int* __restrict__ offs,
                        int* __restrict__ bsum, int n) {
  __shared__ int s[256];
  int i = blockIdx.x * 256 + threadIdx.x;
  int v = (i < n) ? count[i] : 0;
  s[threadIdx.x] = v;
  __syncthreads();
  for (int off = 1; off < 256; off <<= 1) {
    int t = (threadIdx.x >= off) ? s[threadIdx.x - off] : 0;
    __syncthreads();
    s[threadIdx.x] += t;
    __syncthreads();
  }
  if (i < n) offs[i] = s[threadIdx.x] - v;  // exclusive
  if (threadIdx.x == 255) bsum[blockIdx.x] = s[255];
}

__global__ void k_scan2(const int* __restrict__ bsum, int* __restrict__ boff, int nb) {
  __shared__ int s[512];
  int t = threadIdx.x;  // single block of 512
  int v = (t < nb) ? bsum[t] : 0;
  s[t] = v;
  __syncthreads();
  for (int off = 1; off < 512; off <<= 1) {
    int u = (t >= off) ? s[t - off] : 0;
    __syncthreads();
    s[t] += u;
    __syncthreads();
  }
  boff[t] = s[t] - v;  // exclusive
}

__global__ void k_scan3(int* __restrict__ offs, const int* __restrict__ boff,
                        int* __restrict__ cursor, int n, int E_) {
  int i = blockIdx.x * 256 + threadIdx.x;
  if (i < n) {
    int o = offs[i] + boff[blockIdx.x];
    offs[i] = o;
    cursor[i] = o;
  }
  if (i == 0) offs[n] = E_;
}

// ---------------- CSR build: scatter ----------------
__global__ void k_scatter(const int* __restrict__ src, const int* __restrict__ dst,
                          int* __restrict__ cursor, int* __restrict__ csr, int E_) {
  int stride = gridDim.x * blockDim.x;
  for (int e = blockIdx.x * blockDim.x + threadIdx.x; e < E_; e += stride) {
    int pos = atomicAdd(&cursor[dst[e]], 1);
    csr[pos] = src[e];
  }
}

// ---------------- fused GAT: online softmax + aggregate + ELU + pool ----------------
__global__ __launch_bounds__(256) void k_gat(
    const int* __restrict__ csr, const int* __restrict__ offs,
    const float* __restrict__ xw, const float* __restrict__ a_src,
    const float* __restrict__ a_dst, const float* __restrict__ bias,
    const int* __restrict__ batch, float* __restrict__ gsum,
    float* __restrict__ cnt, int n) {
  int wave = (blockIdx.x * blockDim.x + threadIdx.x) >> 6;
  int lane = threadIdx.x & 63;
  if (wave >= n) return;
  int i = wave;
  int hc = lane < HC ? lane : HC - 1;
  int h = hc / C;
  float adst = a_dst[i * H + h];
  int beg = offs[i], end = offs[i + 1];
  float m = -INFINITY, d = 0.f, acc = 0.f;
  // k = beg-1 is the virtual self-loop (j = i)
  for (int k = beg - 1; k < end; ++k) {
    int j = (k < beg) ? i : csr[k];
    float z = a_src[j * H + h] + adst;
    z = z > 0.f ? z : NEG_SLOPE * z;
    float xv = xw[(size_t)j * HC + hc];
    float mn = fmaxf(m, z);
    float s = __expf(m - mn);  // exp(-inf)=0 on first iter
    float p = __expf(z - mn);
    d = d * s + p;
    acc = acc * s + p * xv;
    m = mn;
  }
  float v = acc / d + bias[hc];
  v = v > 0.f ? v : __expf(v) - 1.f;  // ELU
  if (lane < HC) {
    int b = batch[i];
    atomicAdd(&gsum[b * HC + hc], v);
    if (lane == 0) atomicAdd(&cnt[b], 1.f);
  }
}

// ---------------- mean + linear + sigmoid ----------------
__global__ void k_final(const float* __restrict__ gsum, const float* __restrict__ cnt,
                        const float* __restrict__ lin_w, const float* __restrict__ lin_b,
                        float* __restrict__ out) {
  int g = blockIdx.x;
  int t = threadIdx.x;  // 64 threads
  float c = fmaxf(cnt[g], 1.f);
  float p = 0.f;
  if (t < HC) {
    float hv = gsum[g * HC + t] / c;
    out[g * HC + t] = hv;
    p = hv * lin_w[t];
  }
#pragma unroll
  for (int off = 32; off > 0; off >>= 1) p += __shfl_down(p, off);
  if (t == 0) out[NG * HC + g] = 1.f / (1.f + __expf(-(p + lin_b[0])));
}

extern "C" void kernel_launch(void* const* d_in, const int* in_sizes, int n_in,
                              void* d_out, int out_size, void* d_ws, size_t ws_size,
                              hipStream_t stream) {
  const float* x       = (const float*)d_in[0];
  const float* W       = (const float*)d_in[1];
  const float* att_src = (const float*)d_in[2];
  const float* att_dst = (const float*)d_in[3];
  const float* bias    = (const float*)d_in[4];
  const float* lin_w   = (const float*)d_in[5];
  const float* lin_b   = (const float*)d_in[6];
  const int*   eidx    = (const int*)d_in[7];
  const int*   batch   = (const int*)d_in[8];

  int n  = in_sizes[0] / DIM;   // 100000
  int E_ = in_sizes[7] / 2;     // 1600000
  const int* srcp = eidx;
  const int* dstp = eidx + E_;

  // workspace carve (bytes)
  char* p = (char*)d_ws;
  float* xw    = (float*)p; p += (size_t)n * HC * sizeof(float);
  float* a_src = (float*)p; p += (size_t)n * H * sizeof(float);
  float* a_dst = (float*)p; p += (size_t)n * H * sizeof(float);
  float* gsum  = (float*)p; p += NG * HC * sizeof(float);
  float* cnt   = (float*)p; p += NG * sizeof(float);
  int* count   = (int*)p;   p += (size_t)(n + 1) * sizeof(int);
  int* offs    = (int*)p;   p += (size_t)(n + 1) * sizeof(int);
  int* cursor  = (int*)p;   p += (size_t)n * sizeof(int);
  int* bsum    = (int*)p;   p += 512 * sizeof(int);
  int* boff    = (int*)p;   p += 512 * sizeof(int);
  int* csr     = (int*)p;   p += (size_t)E_ * sizeof(int);

  float* out = (float*)d_out;

  const int T = 256;
  int nb = (n + 255) / 256;  // 391 scan blocks (<=512)

  k_zero<<<128, T, 0, stream>>>(count, gsum, cnt, n);
  k_xw<<<2560, T, 0, stream>>>(x, W, xw, n);
  k_att<<<(n * H + T - 1) / T, T, 0, stream>>>(xw, att_src, att_dst, a_src, a_dst, n);
  k_hist<<<1024, T, 0, stream>>>(dstp, count, E_);
  k_scan1<<<nb, 256, 0, stream>>>(count, offs, bsum, n);
  k_scan2<<<1, 512, 0, stream>>>(bsum, boff, nb);
  k_scan3<<<nb, 256, 0, stream>>>(offs, boff, cursor, n, E_);
  k_scatter<<<1024, T, 0, stream>>>(srcp, dstp, cursor, csr, E_);
  k_gat<<<(n * 64 + T - 1) / T, T, 0, stream>>>(csr, offs, xw, a_src, a_dst, bias, batch, gsum, cnt, n);
  k_final<<<NG, 64, 0, stream>>>(gsum, cnt, lin_w, lin_b, out);
}

// Round 3
// 875.107 us; speedup vs baseline: 4.6296x; 1.0505x over previous
//
#include <hip/hip_runtime.h>
#include <math.h>

#define DIM 128
#define H 5
#define C 10
#define HC 50
#define NG 256
#define NEG_SLOPE 0.2f

// ---------------- zero init ----------------
__global__ void k_zero(int* __restrict__ count, float* __restrict__ gsum,
                       float* __restrict__ cnt, int n) {
  int i = blockIdx.x * blockDim.x + threadIdx.x;
  int stride = gridDim.x * blockDim.x;
  for (int k = i; k < n + 1; k += stride) count[k] = 0;
  if (i < NG * HC) gsum[i] = 0.f;
  if (i < NG) cnt[i] = 0.f;
}

// ---------------- xw = x @ W ----------------
__global__ void k_xw(const float* __restrict__ x, const float* __restrict__ W,
                     float* __restrict__ xw, int n) {
  __shared__ float sW[DIM * HC];  // 25.6 KB
  for (int i = threadIdx.x; i < DIM * HC; i += blockDim.x) sW[i] = W[i];
  __syncthreads();
  int total = n * HC;
  int stride = gridDim.x * blockDim.x;
  for (int idx = blockIdx.x * blockDim.x + threadIdx.x; idx < total; idx += stride) {
    int row = idx / HC, col = idx - row * HC;
    const float* xr = x + (size_t)row * DIM;
    float acc = 0.f;
#pragma unroll 8
    for (int k = 0; k < DIM; ++k) acc += xr[k] * sW[k * HC + col];
    xw[idx] = acc;
  }
}

// ---------------- a_src / a_dst ----------------
__global__ void k_att(const float* __restrict__ xw, const float* __restrict__ att_src,
                      const float* __restrict__ att_dst, float* __restrict__ a_src,
                      float* __restrict__ a_dst, int n) {
  int total = n * H;
  int stride = gridDim.x * blockDim.x;
  for (int idx = blockIdx.x * blockDim.x + threadIdx.x; idx < total; idx += stride) {
    int node = idx / H, h = idx - node * H;
    const float* row = xw + (size_t)node * HC + h * C;
    float s = 0.f, d = 0.f;
#pragma unroll
    for (int c = 0; c < C; ++c) {
      float v = row[c];
      s += v * att_src[h * C + c];
      d += v * att_dst[h * C + c];
    }
    a_src[idx] = s;
    a_dst[idx] = d;
  }
}

// ---------------- CSR build: histogram ----------------
__global__ void k_hist(const int* __restrict__ dst, int* __restrict__ count, int E_) {
  int stride = gridDim.x * blockDim.x;
  for (int e = blockIdx.x * blockDim.x + threadIdx.x; e < E_; e += stride)
    atomicAdd(&count[dst[e]], 1);
}

// ---------------- CSR build: 2-level exclusive scan ----------------
__global__ void k_scan1(const int* __restrict__ count, int* __restrict__ offs,
                        int* __restrict__ bsum, int n) {
  __shared__ int s[256];
  int i = blockIdx.x * 256 + threadIdx.x;
  int v = (i < n) ? count[i] : 0;
  s[threadIdx.x] = v;
  __syncthreads();
  for (int off = 1; off < 256; off <<= 1) {
    int t = (threadIdx.x >= off) ? s[threadIdx.x - off] : 0;
    __syncthreads();
    s[threadIdx.x] += t;
    __syncthreads();
  }
  if (i < n) offs[i] = s[threadIdx.x] - v;  // exclusive
  if (threadIdx.x == 255) bsum[blockIdx.x] = s[255];
}

__global__ void k_scan2(const int* __restrict__ bsum, int* __restrict__ boff, int nb) {
  __shared__ int s[512];
  int t = threadIdx.x;  // single block of 512
  int v = (t < nb) ? bsum[t] : 0;
  s[t] = v;
  __syncthreads();
  for (int off = 1; off < 512; off <<= 1) {
    int u = (t >= off) ? s[t - off] : 0;
    __syncthreads();
    s[t] += u;
    __syncthreads();
  }
  boff[t] = s[t] - v;  // exclusive
}

__global__ void k_scan3(int* __restrict__ offs, const int* __restrict__ boff,
                        int* __restrict__ cursor, int n, int E_) {
  int i = blockIdx.x * 256 + threadIdx.x;
  if (i < n) {
    int o = offs[i] + boff[blockIdx.x];
    offs[i] = o;
    cursor[i] = o;
  }
  if (i == 0) offs[n] = E_;
}

// ---------------- CSR build: scatter ----------------
__global__ void k_scatter(const int* __restrict__ src, const int* __restrict__ dst,
                          int* __restrict__ cursor, int* __restrict__ csr, int E_) {
  int stride = gridDim.x * blockDim.x;
  for (int e = blockIdx.x * blockDim.x + threadIdx.x; e < E_; e += stride) {
    int pos = atomicAdd(&cursor[dst[e]], 1);
    csr[pos] = src[e];
  }
}

// ---------------- fused GAT: online softmax + aggregate + ELU + pool ----------------
#define UNR 8
__global__ __launch_bounds__(256) void k_gat(
    const int* __restrict__ csr, const int* __restrict__ offs,
    const float* __restrict__ xw, const float* __restrict__ a_src,
    const float* __restrict__ a_dst, const float* __restrict__ bias,
    const int* __restrict__ batch, float* __restrict__ gsum,
    float* __restrict__ cnt, int n) {
  int wave = (blockIdx.x * blockDim.x + threadIdx.x) >> 6;
  int lane = threadIdx.x & 63;
  if (wave >= n) return;
  int i = wave;
  int hc = lane < HC ? lane : HC - 1;
  int h = hc / C;
  float adst = a_dst[i * H + h];
  int beg = offs[i], end = offs[i + 1];

  // self-loop as initial state: exp(z_self - m) == 1
  float zs = a_src[i * H + h] + adst;
  zs = zs > 0.f ? zs : NEG_SLOPE * zs;
  float m = zs, d = 1.f, acc = xw[(size_t)i * HC + hc];

  int k = beg;
  for (; k + UNR <= end; k += UNR) {
    int jj[UNR];
#pragma unroll
    for (int u = 0; u < UNR; ++u) jj[u] = csr[k + u];
    float zz[UNR], xv[UNR];
#pragma unroll
    for (int u = 0; u < UNR; ++u) {
      float z = a_src[jj[u] * H + h] + adst;
      zz[u] = z > 0.f ? z : NEG_SLOPE * z;
      xv[u] = xw[(size_t)jj[u] * HC + hc];
    }
#pragma unroll
    for (int u = 0; u < UNR; ++u) {
      float mn = fmaxf(m, zz[u]);
      float s = __expf(m - mn);
      float p = __expf(zz[u] - mn);
      d = d * s + p;
      acc = acc * s + p * xv[u];
      m = mn;
    }
  }
  for (; k < end; ++k) {
    int j = csr[k];
    float z = a_src[j * H + h] + adst;
    z = z > 0.f ? z : NEG_SLOPE * z;
    float xv = xw[(size_t)j * HC + hc];
    float mn = fmaxf(m, z);
    float s = __expf(m - mn);
    float p = __expf(z - mn);
    d = d * s + p;
    acc = acc * s + p * xv;
    m = mn;
  }

  float v = acc / d + bias[hc];
  v = v > 0.f ? v : __expf(v) - 1.f;  // ELU
  if (lane < HC) {
    int b = batch[i];
    atomicAdd(&gsum[b * HC + hc], v);
    if (lane == 0) atomicAdd(&cnt[b], 1.f);
  }
}

// ---------------- mean + linear + sigmoid ----------------
__global__ void k_final(const float* __restrict__ gsum, const float* __restrict__ cnt,
                        const float* __restrict__ lin_w, const float* __restrict__ lin_b,
                        float* __restrict__ out) {
  int g = blockIdx.x;
  int t = threadIdx.x;  // 64 threads
  float c = fmaxf(cnt[g], 1.f);
  float p = 0.f;
  if (t < HC) {
    float hv = gsum[g * HC + t] / c;
    out[g * HC + t] = hv;
    p = hv * lin_w[t];
  }
#pragma unroll
  for (int off = 32; off > 0; off >>= 1) p += __shfl_down(p, off);
  if (t == 0) out[NG * HC + g] = 1.f / (1.f + __expf(-(p + lin_b[0])));
}

extern "C" void kernel_launch(void* const* d_in, const int* in_sizes, int n_in,
                              void* d_out, int out_size, void* d_ws, size_t ws_size,
                              hipStream_t stream) {
  const float* x       = (const float*)d_in[0];
  const float* W       = (const float*)d_in[1];
  const float* att_src = (const float*)d_in[2];
  const float* att_dst = (const float*)d_in[3];
  const float* bias    = (const float*)d_in[4];
  const float* lin_w   = (const float*)d_in[5];
  const float* lin_b   = (const float*)d_in[6];
  const int*   eidx    = (const int*)d_in[7];
  const int*   batch   = (const int*)d_in[8];

  int n  = in_sizes[0] / DIM;   // 100000
  int E_ = in_sizes[7] / 2;     // 1600000
  const int* srcp = eidx;
  const int* dstp = eidx + E_;

  // workspace carve (bytes)
  char* p = (char*)d_ws;
  float* xw    = (float*)p; p += (size_t)n * HC * sizeof(float);
  float* a_src = (float*)p; p += (size_t)n * H * sizeof(float);
  float* a_dst = (float*)p; p += (size_t)n * H * sizeof(float);
  float* gsum  = (float*)p; p += NG * HC * sizeof(float);
  float* cnt   = (float*)p; p += NG * sizeof(float);
  int* count   = (int*)p;   p += (size_t)(n + 1) * sizeof(int);
  int* offs    = (int*)p;   p += (size_t)(n + 1) * sizeof(int);
  int* cursor  = (int*)p;   p += (size_t)n * sizeof(int);
  int* bsum    = (int*)p;   p += 512 * sizeof(int);
  int* boff    = (int*)p;   p += 512 * sizeof(int);
  int* csr     = (int*)p;   p += (size_t)E_ * sizeof(int);

  float* out = (float*)d_out;

  const int T = 256;
  int nb = (n + 255) / 256;  // 391 scan blocks (<=512)

  k_zero<<<128, T, 0, stream>>>(count, gsum, cnt, n);
  k_xw<<<2560, T, 0, stream>>>(x, W, xw, n);
  k_att<<<(n * H + T - 1) / T, T, 0, stream>>>(xw, att_src, att_dst, a_src, a_dst, n);
  k_hist<<<1024, T, 0, stream>>>(dstp, count, E_);
  k_scan1<<<nb, 256, 0, stream>>>(count, offs, bsum, n);
  k_scan2<<<1, 512, 0, stream>>>(bsum, boff, nb);
  k_scan3<<<nb, 256, 0, stream>>>(offs, boff, cursor, n, E_);
  k_scatter<<<1024, T, 0, stream>>>(srcp, dstp, cursor, csr, E_);
  k_gat<<<(n * 64 + T - 1) / T, T, 0, stream>>>(csr, offs, xw, a_src, a_dst, bias, batch, gsum, cnt, n);
  k_final<<<NG, 64, 0, stream>>>(gsum, cnt, lin_w, lin_b, out);
}

// Round 4
// 815.330 us; speedup vs baseline: 4.9690x; 1.0733x over previous
//
#include <hip/hip_runtime.h>
#include <hip/hip_bf16.h>
#include <math.h>

#define DIM 128
#define H 5
#define C 10
#define HC 50
#define NG 256
#define NEG_SLOPE 0.2f
#define UNR 16

// ---------------- zero init ----------------
__global__ void k_zero(int* __restrict__ count, float* __restrict__ gsum,
                       float* __restrict__ cnt, int n) {
  int i = blockIdx.x * blockDim.x + threadIdx.x;
  int stride = gridDim.x * blockDim.x;
  for (int k = i; k < n + 1; k += stride) count[k] = 0;
  if (i < NG * HC) gsum[i] = 0.f;
  if (i < NG) cnt[i] = 0.f;
}

// ---------------- xw = x @ W ----------------
__global__ void k_xw(const float* __restrict__ x, const float* __restrict__ W,
                     float* __restrict__ xw, int n) {
  __shared__ float sW[DIM * HC];  // 25.6 KB
  for (int i = threadIdx.x; i < DIM * HC; i += blockDim.x) sW[i] = W[i];
  __syncthreads();
  int total = n * HC;
  int stride = gridDim.x * blockDim.x;
  for (int idx = blockIdx.x * blockDim.x + threadIdx.x; idx < total; idx += stride) {
    int row = idx / HC, col = idx - row * HC;
    const float* xr = x + (size_t)row * DIM;
    float acc = 0.f;
#pragma unroll 8
    for (int k = 0; k < DIM; ++k) acc += xr[k] * sW[k * HC + col];
    xw[idx] = acc;
  }
}

// ---------------- a_src / a_dst ----------------
__global__ void k_att(const float* __restrict__ xw, const float* __restrict__ att_src,
                      const float* __restrict__ att_dst, float* __restrict__ a_src,
                      float* __restrict__ a_dst, int n) {
  int total = n * H;
  int stride = gridDim.x * blockDim.x;
  for (int idx = blockIdx.x * blockDim.x + threadIdx.x; idx < total; idx += stride) {
    int node = idx / H, h = idx - node * H;
    const float* row = xw + (size_t)node * HC + h * C;
    float s = 0.f, d = 0.f;
#pragma unroll
    for (int c = 0; c < C; ++c) {
      float v = row[c];
      s += v * att_src[h * C + c];
      d += v * att_dst[h * C + c];
    }
    a_src[idx] = s;
    a_dst[idx] = d;
  }
}

// ---------------- pack per-node bf16 record: [xw(50)|a_src(5)|a_dst(5)|0(4)] ----------------
__global__ void k_pack(const float* __restrict__ xw, const float* __restrict__ a_src,
                       const float* __restrict__ a_dst, __hip_bfloat16* __restrict__ rec,
                       int n) {
  int t = blockIdx.x * blockDim.x + threadIdx.x;
  int i = t >> 6, lane = t & 63;
  if (i >= n) return;
  float v = 0.f;
  if (lane < HC) v = xw[(size_t)i * HC + lane];
  else if (lane < 55) v = a_src[i * H + (lane - 50)];
  else if (lane < 60) v = a_dst[i * H + (lane - 55)];
  rec[((size_t)i << 6) + lane] = __float2bfloat16(v);
}

// ---------------- CSR build: histogram ----------------
__global__ void k_hist(const int* __restrict__ dst, int* __restrict__ count, int E_) {
  int stride = gridDim.x * blockDim.x;
  for (int e = blockIdx.x * blockDim.x + threadIdx.x; e < E_; e += stride)
    atomicAdd(&count[dst[e]], 1);
}

// ---------------- CSR build: 2-level exclusive scan ----------------
__global__ void k_scan1(const int* __restrict__ count, int* __restrict__ offs,
                        int* __restrict__ bsum, int n) {
  __shared__ int s[256];
  int i = blockIdx.x * 256 + threadIdx.x;
  int v = (i < n) ? count[i] : 0;
  s[threadIdx.x] = v;
  __syncthreads();
  for (int off = 1; off < 256; off <<= 1) {
    int t = (threadIdx.x >= off) ? s[threadIdx.x - off] : 0;
    __syncthreads();
    s[threadIdx.x] += t;
    __syncthreads();
  }
  if (i < n) offs[i] = s[threadIdx.x] - v;  // exclusive
  if (threadIdx.x == 255) bsum[blockIdx.x] = s[255];
}

__global__ void k_scan2(const int* __restrict__ bsum, int* __restrict__ boff, int nb) {
  __shared__ int s[512];
  int t = threadIdx.x;  // single block of 512
  int v = (t < nb) ? bsum[t] : 0;
  s[t] = v;
  __syncthreads();
  for (int off = 1; off < 512; off <<= 1) {
    int u = (t >= off) ? s[t - off] : 0;
    __syncthreads();
    s[t] += u;
    __syncthreads();
  }
  boff[t] = s[t] - v;  // exclusive
}

__global__ void k_scan3(int* __restrict__ offs, const int* __restrict__ boff,
                        int* __restrict__ cursor, int n, int E_) {
  int i = blockIdx.x * 256 + threadIdx.x;
  if (i < n) {
    int o = offs[i] + boff[blockIdx.x];
    offs[i] = o;
    cursor[i] = o;
  }
  if (i == 0) offs[n] = E_;
}

// ---------------- CSR build: scatter ----------------
__global__ void k_scatter(const int* __restrict__ src, const int* __restrict__ dst,
                          int* __restrict__ cursor, int* __restrict__ csr, int E_) {
  int stride = gridDim.x * blockDim.x;
  for (int e = blockIdx.x * blockDim.x + threadIdx.x; e < E_; e += stride) {
    int pos = atomicAdd(&cursor[dst[e]], 1);
    csr[pos] = src[e];
  }
}

// ---------------- fused GAT: online softmax + aggregate + ELU + pool ----------------
__global__ __launch_bounds__(256) void k_gat(
    const int* __restrict__ csr, const int* __restrict__ offs,
    const __hip_bfloat16* __restrict__ rec, const float* __restrict__ bias,
    const int* __restrict__ batch, float* __restrict__ gsum,
    float* __restrict__ cnt, int n) {
  int wave = (blockIdx.x * blockDim.x + threadIdx.x) >> 6;
  int lane = threadIdx.x & 63;
  if (wave >= n) return;
  int i = wave;
  int hc = lane < HC ? lane : HC - 1;
  int h = hc / C;

  // self-loop from own record
  float rv = __bfloat162float(rec[((size_t)i << 6) + lane]);
  float asi = __shfl(rv, 50 + h);
  float adi = __shfl(rv, 55 + h);
  float zs = asi + adi;
  zs = zs > 0.f ? zs : NEG_SLOPE * zs;
  float m = zs, d = 1.f, acc = rv;

  int beg = offs[i], end = offs[i + 1];
  if (beg < end) {
    int lidx = lane & (UNR - 1);
    int jraw = csr[min(beg + lidx, end - 1)];  // cooperative idx load (1 line)
    for (int k0 = beg; k0 < end; k0 += UNR) {
      float val[UNR];
#pragma unroll
      for (int u = 0; u < UNR; ++u) {
        int ju = __builtin_amdgcn_readlane(jraw, u);  // uniform -> saddr gather
        val[u] = __bfloat162float(rec[((size_t)ju << 6) + lane]);
      }
      int k1 = k0 + UNR;
      int jnext = 0;
      if (k1 < end) jnext = csr[min(k1 + lidx, end - 1)];  // prefetch next idx block
#pragma unroll
      for (int u = 0; u < UNR; ++u) {
        float asj = __shfl(val[u], 50 + h);
        float z = asj + adi;
        z = z > 0.f ? z : NEG_SLOPE * z;
        z = (k0 + u < end) ? z : -INFINITY;  // predicated tail: p=0, m unchanged
        float mn = fmaxf(m, z);
        float s = __expf(m - mn);
        float p = __expf(z - mn);
        d = d * s + p;
        acc = acc * s + p * val[u];
        m = mn;
      }
      jraw = jnext;
    }
  }

  float v = acc / d + bias[hc];
  v = v > 0.f ? v : __expf(v) - 1.f;  // ELU
  if (lane < HC) {
    int b = batch[i];
    atomicAdd(&gsum[b * HC + hc], v);
    if (lane == 0) atomicAdd(&cnt[b], 1.f);
  }
}

// ---------------- mean + linear + sigmoid ----------------
__global__ void k_final(const float* __restrict__ gsum, const float* __restrict__ cnt,
                        const float* __restrict__ lin_w, const float* __restrict__ lin_b,
                        float* __restrict__ out) {
  int g = blockIdx.x;
  int t = threadIdx.x;  // 64 threads
  float c = fmaxf(cnt[g], 1.f);
  float p = 0.f;
  if (t < HC) {
    float hv = gsum[g * HC + t] / c;
    out[g * HC + t] = hv;
    p = hv * lin_w[t];
  }
#pragma unroll
  for (int off = 32; off > 0; off >>= 1) p += __shfl_down(p, off);
  if (t == 0) out[NG * HC + g] = 1.f / (1.f + __expf(-(p + lin_b[0])));
}

extern "C" void kernel_launch(void* const* d_in, const int* in_sizes, int n_in,
                              void* d_out, int out_size, void* d_ws, size_t ws_size,
                              hipStream_t stream) {
  const float* x       = (const float*)d_in[0];
  const float* W       = (const float*)d_in[1];
  const float* att_src = (const float*)d_in[2];
  const float* att_dst = (const float*)d_in[3];
  const float* bias    = (const float*)d_in[4];
  const float* lin_w   = (const float*)d_in[5];
  const float* lin_b   = (const float*)d_in[6];
  const int*   eidx    = (const int*)d_in[7];
  const int*   batch   = (const int*)d_in[8];

  int n  = in_sizes[0] / DIM;   // 100000
  int E_ = in_sizes[7] / 2;     // 1600000
  const int* srcp = eidx;
  const int* dstp = eidx + E_;

  // workspace carve (bytes)
  char* p = (char*)d_ws;
  float* xw    = (float*)p; p += (size_t)n * HC * sizeof(float);
  float* a_src = (float*)p; p += (size_t)n * H * sizeof(float);
  float* a_dst = (float*)p; p += (size_t)n * H * sizeof(float);
  float* gsum  = (float*)p; p += NG * HC * sizeof(float);
  float* cnt   = (float*)p; p += NG * sizeof(float);
  int* count   = (int*)p;   p += (size_t)(n + 1) * sizeof(int);
  int* offs    = (int*)p;   p += (size_t)(n + 1) * sizeof(int);
  int* cursor  = (int*)p;   p += (size_t)n * sizeof(int);
  int* bsum    = (int*)p;   p += 512 * sizeof(int);
  int* boff    = (int*)p;   p += 512 * sizeof(int);
  int* csr     = (int*)p;   p += (size_t)E_ * sizeof(int);
  __hip_bfloat16* rec = (__hip_bfloat16*)p; p += (size_t)n * 64 * sizeof(__hip_bfloat16);

  float* out = (float*)d_out;

  const int T = 256;
  int nb = (n + 255) / 256;  // 391 scan blocks (<=512)

  k_zero<<<128, T, 0, stream>>>(count, gsum, cnt, n);
  k_xw<<<2560, T, 0, stream>>>(x, W, xw, n);
  k_att<<<(n * H + T - 1) / T, T, 0, stream>>>(xw, att_src, att_dst, a_src, a_dst, n);
  k_pack<<<(n * 64 + T - 1) / T, T, 0, stream>>>(xw, a_src, a_dst, rec, n);
  k_hist<<<1024, T, 0, stream>>>(dstp, count, E_);
  k_scan1<<<nb, 256, 0, stream>>>(count, offs, bsum, n);
  k_scan2<<<1, 512, 0, stream>>>(bsum, boff, nb);
  k_scan3<<<nb, 256, 0, stream>>>(offs, boff, cursor, n, E_);
  k_scatter<<<1024, T, 0, stream>>>(srcp, dstp, cursor, csr, E_);
  k_gat<<<(n * 64 + T - 1) / T, T, 0, stream>>>(csr, offs, rec, bias, batch, gsum, cnt, n);
  k_final<<<NG, 64, 0, stream>>>(gsum, cnt, lin_w, lin_b, out);
}

// Round 5
// 554.409 us; speedup vs baseline: 7.3075x; 1.4706x over previous
//
#include <hip/hip_runtime.h>
#include <hip/hip_bf16.h>
#include <math.h>

#define DIM 128
#define H 5
#define C 10
#define HC 50
#define NG 256
#define NEG_SLOPE 0.2f
#define UNR 16

// ---------------- zero init (histogram counters only) ----------------
__global__ void k_zero(int* __restrict__ count, int n) {
  int stride = gridDim.x * blockDim.x;
  for (int k = blockIdx.x * blockDim.x + threadIdx.x; k < n + 1; k += stride) count[k] = 0;
}

// ---------------- xw = x @ W ----------------
__global__ void k_xw(const float* __restrict__ x, const float* __restrict__ W,
                     float* __restrict__ xw, int n) {
  __shared__ float sW[DIM * HC];  // 25.6 KB
  for (int i = threadIdx.x; i < DIM * HC; i += blockDim.x) sW[i] = W[i];
  __syncthreads();
  int total = n * HC;
  int stride = gridDim.x * blockDim.x;
  for (int idx = blockIdx.x * blockDim.x + threadIdx.x; idx < total; idx += stride) {
    int row = idx / HC, col = idx - row * HC;
    const float* xr = x + (size_t)row * DIM;
    float acc = 0.f;
#pragma unroll 8
    for (int k = 0; k < DIM; ++k) acc += xr[k] * sW[k * HC + col];
    xw[idx] = acc;
  }
}

// ---------------- a_src / a_dst ----------------
__global__ void k_att(const float* __restrict__ xw, const float* __restrict__ att_src,
                      const float* __restrict__ att_dst, float* __restrict__ a_src,
                      float* __restrict__ a_dst, int n) {
  int total = n * H;
  int stride = gridDim.x * blockDim.x;
  for (int idx = blockIdx.x * blockDim.x + threadIdx.x; idx < total; idx += stride) {
    int node = idx / H, h = idx - node * H;
    const float* row = xw + (size_t)node * HC + h * C;
    float s = 0.f, d = 0.f;
#pragma unroll
    for (int c = 0; c < C; ++c) {
      float v = row[c];
      s += v * att_src[h * C + c];
      d += v * att_dst[h * C + c];
    }
    a_src[idx] = s;
    a_dst[idx] = d;
  }
}

// ---------------- pack per-node bf16 record: [xw(50)|a_src(5)|a_dst(5)|0(4)] ----------------
__global__ void k_pack(const float* __restrict__ xw, const float* __restrict__ a_src,
                       const float* __restrict__ a_dst, __hip_bfloat16* __restrict__ rec,
                       int n) {
  int t = blockIdx.x * blockDim.x + threadIdx.x;
  int i = t >> 6, lane = t & 63;
  if (i >= n) return;
  float v = 0.f;
  if (lane < HC) v = xw[(size_t)i * HC + lane];
  else if (lane < 55) v = a_src[i * H + (lane - 50)];
  else if (lane < 60) v = a_dst[i * H + (lane - 55)];
  rec[((size_t)i << 6) + lane] = __float2bfloat16(v);
}

// ---------------- CSR build: histogram ----------------
__global__ void k_hist(const int* __restrict__ dst, int* __restrict__ count, int E_) {
  int stride = gridDim.x * blockDim.x;
  for (int e = blockIdx.x * blockDim.x + threadIdx.x; e < E_; e += stride)
    atomicAdd(&count[dst[e]], 1);
}

// ---------------- CSR build: 2-level exclusive scan ----------------
__global__ void k_scan1(const int* __restrict__ count, int* __restrict__ offs,
                        int* __restrict__ bsum, int n) {
  __shared__ int s[256];
  int i = blockIdx.x * 256 + threadIdx.x;
  int v = (i < n) ? count[i] : 0;
  s[threadIdx.x] = v;
  __syncthreads();
  for (int off = 1; off < 256; off <<= 1) {
    int t = (threadIdx.x >= off) ? s[threadIdx.x - off] : 0;
    __syncthreads();
    s[threadIdx.x] += t;
    __syncthreads();
  }
  if (i < n) offs[i] = s[threadIdx.x] - v;  // exclusive
  if (threadIdx.x == 255) bsum[blockIdx.x] = s[255];
}

__global__ void k_scan2(const int* __restrict__ bsum, int* __restrict__ boff, int nb) {
  __shared__ int s[512];
  int t = threadIdx.x;  // single block of 512
  int v = (t < nb) ? bsum[t] : 0;
  s[t] = v;
  __syncthreads();
  for (int off = 1; off < 512; off <<= 1) {
    int u = (t >= off) ? s[t - off] : 0;
    __syncthreads();
    s[t] += u;
    __syncthreads();
  }
  boff[t] = s[t] - v;  // exclusive
}

__global__ void k_scan3(int* __restrict__ offs, const int* __restrict__ boff,
                        int* __restrict__ cursor, int n, int E_) {
  int i = blockIdx.x * 256 + threadIdx.x;
  if (i < n) {
    int o = offs[i] + boff[blockIdx.x];
    offs[i] = o;
    cursor[i] = o;
  }
  if (i == 0) offs[n] = E_;
}

// ---------------- CSR build: scatter ----------------
__global__ void k_scatter(const int* __restrict__ src, const int* __restrict__ dst,
                          int* __restrict__ cursor, int* __restrict__ csr, int E_) {
  int stride = gridDim.x * blockDim.x;
  for (int e = blockIdx.x * blockDim.x + threadIdx.x; e < E_; e += stride) {
    int pos = atomicAdd(&cursor[dst[e]], 1);
    csr[pos] = src[e];
  }
}

// ---------------- fused GAT: online softmax + aggregate + ELU (no atomics) ----------------
__global__ __launch_bounds__(256) void k_gat(
    const int* __restrict__ csr, const int* __restrict__ offs,
    const __hip_bfloat16* __restrict__ rec, const float* __restrict__ bias,
    float* __restrict__ out_node, int n) {
  int wave = (blockIdx.x * blockDim.x + threadIdx.x) >> 6;
  int lane = threadIdx.x & 63;
  if (wave >= n) return;
  int i = wave;
  int hc = lane < HC ? lane : HC - 1;
  int h = hc / C;

  // self-loop from own record
  float rv = __bfloat162float(rec[((size_t)i << 6) + lane]);
  float adi = __shfl(rv, 55 + h);
  float zs = __shfl(rv, 50 + h) + adi;
  zs = zs > 0.f ? zs : NEG_SLOPE * zs;
  float m = zs, d = 1.f, acc = rv;

  int beg = offs[i], end = offs[i + 1];
  for (int c0 = beg; c0 < end; c0 += 64) {
    int cend = min(end - c0, 64);
    int jraw = csr[min(c0 + lane, end - 1)];  // up to 64 idx in one coop load
    for (int s0 = 0; s0 < cend; s0 += UNR) {
      float val[UNR], z[UNR];
#pragma unroll
      for (int u = 0; u < UNR; ++u) {
        int ju = __builtin_amdgcn_readlane(jraw, s0 + u);  // uniform -> saddr gather
        val[u] = __bfloat162float(rec[((size_t)ju << 6) + lane]);
      }
#pragma unroll
      for (int u = 0; u < UNR; ++u) {
        float zz = __shfl(val[u], 50 + h) + adi;
        zz = zz > 0.f ? zz : NEG_SLOPE * zz;
        z[u] = (s0 + u < cend) ? zz : -INFINITY;  // predicated tail: p=0
      }
      // tree max (4 levels) instead of 16-deep chain
      float t0 = fmaxf(fmaxf(z[0], z[1]), fmaxf(z[2], z[3]));
      float t1 = fmaxf(fmaxf(z[4], z[5]), fmaxf(z[6], z[7]));
      float t2 = fmaxf(fmaxf(z[8], z[9]), fmaxf(z[10], z[11]));
      float t3 = fmaxf(fmaxf(z[12], z[13]), fmaxf(z[14], z[15]));
      float mn = fmaxf(m, fmaxf(fmaxf(t0, t1), fmaxf(t2, t3)));
      float sc = __expf(m - mn);
      float dp[4] = {0.f, 0.f, 0.f, 0.f}, ap[4] = {0.f, 0.f, 0.f, 0.f};
#pragma unroll
      for (int u = 0; u < UNR; ++u) {
        float p = __expf(z[u] - mn);  // independent exps
        dp[u & 3] += p;
        ap[u & 3] += p * val[u];
      }
      d = d * sc + ((dp[0] + dp[1]) + (dp[2] + dp[3]));
      acc = acc * sc + ((ap[0] + ap[1]) + (ap[2] + ap[3]));
      m = mn;
    }
  }

  float v = acc / d + bias[hc];
  v = v > 0.f ? v : __expf(v) - 1.f;  // ELU
  if (lane < HC) out_node[(size_t)i * HC + hc] = v;  // plain coalesced store
}

// ---------------- atomic-free pooling + linear + sigmoid (one block per graph) ----------------
__global__ __launch_bounds__(256) void k_pool(
    const float* __restrict__ out_node, const int* __restrict__ batch,
    const float* __restrict__ lin_w, const float* __restrict__ lin_b,
    float* __restrict__ out, int n) {
  __shared__ int sb[2];
  __shared__ float sacc[4][HC];
  int g = blockIdx.x;
  int t = threadIdx.x;
  if (t < 2) {  // binary search sorted batch for [start,end)
    int target = g + t, lo = 0, hi = n;
    while (lo < hi) {
      int mid = (lo + hi) >> 1;
      if (batch[mid] < target) lo = mid + 1; else hi = mid;
    }
    sb[t] = lo;
  }
  __syncthreads();
  int s = sb[0], e = sb[1];
  int w = t >> 6, lane = t & 63;
  float a = 0.f;
  if (lane < HC)
    for (int i = s + w; i < e; i += 4) a += out_node[(size_t)i * HC + lane];
  if (lane < HC) sacc[w][lane] = a;
  __syncthreads();
  if (t < HC) {
    float hv = ((sacc[0][t] + sacc[1][t]) + (sacc[2][t] + sacc[3][t])) /
               fmaxf((float)(e - s), 1.f);
    out[g * HC + t] = hv;
    sacc[0][t] = hv * lin_w[t];
  }
  __syncthreads();
  if (t == 0) {
    float p = 0.f;
    for (int c = 0; c < HC; ++c) p += sacc[0][c];
    out[NG * HC + g] = 1.f / (1.f + __expf(-(p + lin_b[0])));
  }
}

extern "C" void kernel_launch(void* const* d_in, const int* in_sizes, int n_in,
                              void* d_out, int out_size, void* d_ws, size_t ws_size,
                              hipStream_t stream) {
  const float* x       = (const float*)d_in[0];
  const float* W       = (const float*)d_in[1];
  const float* att_src = (const float*)d_in[2];
  const float* att_dst = (const float*)d_in[3];
  const float* bias    = (const float*)d_in[4];
  const float* lin_w   = (const float*)d_in[5];
  const float* lin_b   = (const float*)d_in[6];
  const int*   eidx    = (const int*)d_in[7];
  const int*   batch   = (const int*)d_in[8];

  int n  = in_sizes[0] / DIM;   // 100000
  int E_ = in_sizes[7] / 2;     // 1600000
  const int* srcp = eidx;
  const int* dstp = eidx + E_;

  // workspace carve (bytes)
  char* p = (char*)d_ws;
  float* xw    = (float*)p; p += (size_t)n * HC * sizeof(float);
  float* a_src = (float*)p; p += (size_t)n * H * sizeof(float);
  float* a_dst = (float*)p; p += (size_t)n * H * sizeof(float);
  int* count   = (int*)p;   p += (size_t)(n + 1) * sizeof(int);
  int* offs    = (int*)p;   p += (size_t)(n + 1) * sizeof(int);
  int* cursor  = (int*)p;   p += (size_t)n * sizeof(int);
  int* bsum    = (int*)p;   p += 512 * sizeof(int);
  int* boff    = (int*)p;   p += 512 * sizeof(int);
  int* csr     = (int*)p;   p += (size_t)E_ * sizeof(int);
  __hip_bfloat16* rec = (__hip_bfloat16*)p; p += (size_t)n * 64 * sizeof(__hip_bfloat16);
  float* out_node = xw;  // alias: xw dead after k_pack; k_gat reads only rec

  float* out = (float*)d_out;

  const int T = 256;
  int nb = (n + 255) / 256;  // 391 scan blocks (<=512)

  k_zero<<<128, T, 0, stream>>>(count, n);
  k_xw<<<2560, T, 0, stream>>>(x, W, xw, n);
  k_att<<<(n * H + T - 1) / T, T, 0, stream>>>(xw, att_src, att_dst, a_src, a_dst, n);
  k_pack<<<(n * 64 + T - 1) / T, T, 0, stream>>>(xw, a_src, a_dst, rec, n);
  k_hist<<<1024, T, 0, stream>>>(dstp, count, E_);
  k_scan1<<<nb, 256, 0, stream>>>(count, offs, bsum, n);
  k_scan2<<<1, 512, 0, stream>>>(bsum, boff, nb);
  k_scan3<<<nb, 256, 0, stream>>>(offs, boff, cursor, n, E_);
  k_scatter<<<1024, T, 0, stream>>>(srcp, dstp, cursor, csr, E_);
  k_gat<<<(n * 64 + T - 1) / T, T, 0, stream>>>(csr, offs, rec, bias, out_node, n);
  k_pool<<<NG, T, 0, stream>>>(out_node, batch, lin_w, lin_b, out, n);
}